// Round 1
// 632.338 us; speedup vs baseline: 1.0023x; 1.0023x over previous
//
#include <hip/hip_runtime.h>
#include <hip/hip_fp16.h>
#include <math.h>

constexpr int INF_ = 128;  // IN
constexpr int H_   = 4;
constexpr int C_   = 32;
constexpr int R_   = 8;
constexpr int NB_  = 16;   // nodes per block
constexpr int EMAX_ = 512; // staged edges per block (mean ~205, +21 sigma)

typedef _Float16 half2_t __attribute__((ext_vector_type(2)));

__device__ __forceinline__ unsigned short f2h(float f) {
    return __half_as_ushort(__float2half(f));
}
__device__ __forceinline__ float h2f(unsigned short u) {
    return __half2float(__ushort_as_half(u));
}
__device__ __forceinline__ unsigned pack2(float a, float b) {
    return (unsigned)f2h(a) | ((unsigned)f2h(b) << 16);
}
__device__ __forceinline__ float dot2(unsigned a, unsigned b, float c) {
#if __has_builtin(__builtin_amdgcn_fdot2)
    return __builtin_amdgcn_fdot2(__builtin_bit_cast(half2_t, a),
                                  __builtin_bit_cast(half2_t, b), c, false);
#else
    c += h2f((unsigned short)(a & 0xFFFF)) * h2f((unsigned short)(b & 0xFFFF));
    c += h2f((unsigned short)(a >> 16))    * h2f((unsigned short)(b >> 16));
    return c;
#endif
}

// -------------------------------------------------------------------------
// CSR build at 16-node GROUP granularity.
// -------------------------------------------------------------------------
__global__ __launch_bounds__(256) void count_edges(
    const int* __restrict__ ei, int* __restrict__ counts, int E)
{
    int e = blockIdx.x * 256 + threadIdx.x;
    if (e >= E) return;
    int dst = ei[E + e];
    atomicAdd(&counts[dst >> 4], 1);
}

// writes offsets[0..G] AND cursor[0..G) (= offsets copy)
__global__ __launch_bounds__(1024) void scan_offsets(
    const int* __restrict__ counts, int* __restrict__ offsets,
    int* __restrict__ cursor, int G)
{
    __shared__ int wsum[16];
    __shared__ int chunk_tot;
    const int tid  = threadIdx.x;
    const int lane = tid & 63;
    const int wid  = tid >> 6;
    int carry = 0;
    for (int base = 0; base < G; base += 1024) {
        int i = base + tid;
        int v = (i < G) ? counts[i] : 0;
        int s = v;
        #pragma unroll
        for (int d = 1; d < 64; d <<= 1) {
            int t = __shfl_up(s, d, 64);
            if (lane >= d) s += t;
        }
        if (lane == 63) wsum[wid] = s;
        __syncthreads();
        if (tid == 0) {
            int acc = 0;
            #pragma unroll
            for (int w = 0; w < 16; ++w) { int t = wsum[w]; wsum[w] = acc; acc += t; }
            chunk_tot = acc;
        }
        __syncthreads();
        int excl = carry + wsum[wid] + (s - v);
        if (i < G) { offsets[i] = excl; cursor[i] = excl; }
        carry += chunk_tot;
        __syncthreads();
    }
    if (tid == 0) offsets[G] = carry;
}

// packed: src | r<<17 | (dst&15)<<20
__global__ __launch_bounds__(256) void scatter_edges(
    const int* __restrict__ ei, const int* __restrict__ et,
    int* __restrict__ cursor, int* __restrict__ sorted, int E)
{
    int e = blockIdx.x * 256 + threadIdx.x;
    if (e >= E) return;
    int src = ei[e];
    int dst = ei[E + e];
    int r   = et[e];
    int pos = atomicAdd(&cursor[dst >> 4], 1);
    sorted[pos] = src | (r << 17) | ((dst & 15) << 20);
}

// -------------------------------------------------------------------------
// prep_all: one kernel, three disjoint jobs.
//  A [0, 98304): Wt fp16 qkv transpose, swizzled-k order.
//  B [98304, 98304+22528): Wp = 352-col combined node-GEMM weight, fp16
//     k-pair packed; cols 288..351 compute M_i/M_j INLINE from Wi/Wj+natt.
//  C: zero counts[0..G].
// -------------------------------------------------------------------------
__global__ __launch_bounds__(256) void prep_all(
    const float* __restrict__ W_q, const float* __restrict__ W_k,
    const float* __restrict__ W_v,
    const float* __restrict__ Wj,  const float* __restrict__ Wi,
    const float* __restrict__ Wsn, const float* __restrict__ Wself,
    const float* __restrict__ natt,
    unsigned short* __restrict__ Wt,   // [3][8][32][128] fp16
    unsigned* __restrict__ Wp,         // [352][64] fp16 pairs
    int* __restrict__ counts, int G)
{
    int idx = blockIdx.x * 256 + threadIdx.x;
    if (idx < 98304) {
        int mat = idx >> 15;
        int rem = idx & 32767;
        int r   = rem >> 12;
        int c   = (rem >> 7) & 31;
        int m   = rem & 127;
        int k   = (m & 3) * 32 + (m >> 2);
        const float* W = (mat == 0) ? W_q : (mat == 1) ? W_k : W_v;
        Wt[idx] = f2h(W[r * 4096 + k * 32 + c]);
        return;
    }
    int j = idx - 98304;
    if (j < 352 * 64) {
        int col = j >> 6;
        int m   = j & 63;
        float w0, w1;
        if (col < 288) {
            const float* W; int wcol, wstride;
            if (col < 128)      { W = Wj;    wcol = col;       wstride = 128; }
            else if (col < 256) { W = Wsn;   wcol = col - 128; wstride = 128; }
            else                { W = Wself; wcol = col - 256; wstride = 32;  }
            w0 = W[(2 * m)     * wstride + wcol];
            w1 = W[(2 * m + 1) * wstride + wcol];
        } else {
            // inline M_i (cols 288..319) / M_j (320..351):
            // M(d, c) = sum_cc W[d*128 + h*32 + cc] * natt[c*64 + off + cc]
            int which = (col >= 320);
            int c  = col - (which ? 320 : 288);   // 0..31
            int h  = c & 3;
            const float* W   = which ? Wj : Wi;
            const float* att = natt + c * 64 + (which ? 32 : 0);
            float a0 = 0.f, a1 = 0.f;
            const float* w0p = W + (2 * m)     * 128 + h * 32;
            const float* w1p = W + (2 * m + 1) * 128 + h * 32;
            #pragma unroll
            for (int cc = 0; cc < 32; ++cc) {
                float av = att[cc];
                a0 += w0p[cc] * av;
                a1 += w1p[cc] * av;
            }
            w0 = a0; w1 = a1;
        }
        Wp[j] = pack2(w0, w1);
        return;
    }
    j -= 352 * 64;
    if (j <= G) counts[j] = 0;
}

// -------------------------------------------------------------------------
// Fused node GEMMs — fp16 dot2, x tile read ONCE (fp16 in LDS).
//   cg 0..3: h_j fp16 swizzled; cg 4..7: self_node fp16 swizzled;
//   cg 8: self_term fp32 (d_out); cg 9: AI; cg 10: AJ.
// -------------------------------------------------------------------------
__global__ __launch_bounds__(256) void fused_gemm(
    const float* __restrict__ x,
    const unsigned* __restrict__ Wp,    // [352][64] fp16 pairs
    unsigned short* __restrict__ hjb,   // [N*128] fp16 swizzled
    unsigned short* __restrict__ sn16,  // [N*128] fp16 swizzled
    float* __restrict__ self_term,      // = d_out
    float* __restrict__ AI,
    float* __restrict__ AJ,
    int N)
{
    __shared__ unsigned xs[32][64];     // 8 KB fp16 pairs
    const int n0  = blockIdx.x * 32;
    const int tid = threadIdx.x;

    #pragma unroll
    for (int j = 0; j < 4; ++j) {
        int f4   = tid + 256 * j;
        int row  = f4 >> 5;
        int col4 = f4 & 31;
        float4 v = make_float4(0.f, 0.f, 0.f, 0.f);
        if (n0 + row < N)
            v = *(const float4*)(x + (size_t)(n0 + row) * 128 + col4 * 4);
        xs[row][col4 * 2]     = pack2(v.x, v.y);
        xs[row][col4 * 2 + 1] = pack2(v.z, v.w);
    }
    __syncthreads();

    const int c_local = tid & 31;
    const int n_base  = tid >> 5;
    const bool ok0 = (n0 + n_base      < N);
    const bool ok1 = (n0 + n_base +  8 < N);
    const bool ok2 = (n0 + n_base + 16 < N);
    const bool ok3 = (n0 + n_base + 24 < N);

    for (int cg = 0; cg < 11; ++cg) {
        const int col = cg * 32 + c_local;
        const unsigned* wp = Wp + col * 64;

        float acc0 = 0.f, acc1 = 0.f, acc2 = 0.f, acc3 = 0.f;
        for (int m = 0; m < 64; m += 4) {
            uint4 w  = *(const uint4*)(wp + m);
            uint4 x0 = *(const uint4*)&xs[n_base     ][m];
            uint4 x1 = *(const uint4*)&xs[n_base +  8][m];
            uint4 x2 = *(const uint4*)&xs[n_base + 16][m];
            uint4 x3 = *(const uint4*)&xs[n_base + 24][m];
            acc0 = dot2(x0.x, w.x, acc0); acc0 = dot2(x0.y, w.y, acc0);
            acc0 = dot2(x0.z, w.z, acc0); acc0 = dot2(x0.w, w.w, acc0);
            acc1 = dot2(x1.x, w.x, acc1); acc1 = dot2(x1.y, w.y, acc1);
            acc1 = dot2(x1.z, w.z, acc1); acc1 = dot2(x1.w, w.w, acc1);
            acc2 = dot2(x2.x, w.x, acc2); acc2 = dot2(x2.y, w.y, acc2);
            acc2 = dot2(x2.z, w.z, acc2); acc2 = dot2(x2.w, w.w, acc2);
            acc3 = dot2(x3.x, w.x, acc3); acc3 = dot2(x3.y, w.y, acc3);
            acc3 = dot2(x3.z, w.z, acc3); acc3 = dot2(x3.w, w.w, acc3);
        }

        if (cg < 4) {
            int so = c_local * 4 + cg;
            if (ok0) hjb[(size_t)(n0 + n_base     ) * 128 + so] = f2h(acc0);
            if (ok1) hjb[(size_t)(n0 + n_base +  8) * 128 + so] = f2h(acc1);
            if (ok2) hjb[(size_t)(n0 + n_base + 16) * 128 + so] = f2h(acc2);
            if (ok3) hjb[(size_t)(n0 + n_base + 24) * 128 + so] = f2h(acc3);
        } else if (cg < 8) {
            int so = c_local * 4 + (cg - 4);
            if (ok0) sn16[(size_t)(n0 + n_base     ) * 128 + so] = f2h(acc0);
            if (ok1) sn16[(size_t)(n0 + n_base +  8) * 128 + so] = f2h(acc1);
            if (ok2) sn16[(size_t)(n0 + n_base + 16) * 128 + so] = f2h(acc2);
            if (ok3) sn16[(size_t)(n0 + n_base + 24) * 128 + so] = f2h(acc3);
        } else {
            float* outb = (cg == 8) ? self_term : (cg == 9) ? AI : AJ;
            if (ok0) outb[(size_t)(n0 + n_base     ) * 32 + c_local] = acc0;
            if (ok1) outb[(size_t)(n0 + n_base +  8) * 32 + c_local] = acc1;
            if (ok2) outb[(size_t)(n0 + n_base + 16) * 32 + c_local] = acc2;
            if (ok3) outb[(size_t)(n0 + n_base + 24) * 32 + c_local] = acc3;
        }
    }
}

// -------------------------------------------------------------------------
// FUSED edge aggregation + tail, 512 threads / 16 nodes per block.
// LDS ~39.9 KB; walk is software-pipelined 4 deep (clamped indices, no
// scalar remainder path) so 8 gather loads stay in flight per half-wave.
// zh reused for q/k/v (fp16) then delta (fp32); sortbuf reused for psi;
// bcur reused for mskl.
// -------------------------------------------------------------------------
__global__ __launch_bounds__(512, 2) void edge_tail(
    const unsigned short* __restrict__ hjb,  // [N*128] fp16 swizzled
    const unsigned short* __restrict__ sn16, // [N*128] fp16 swizzled
    const float* __restrict__ AJ,        // [N,32]
    const float* __restrict__ AI,        // [N,32]
    const int*   __restrict__ offsets,   // [G+1]
    const int*   __restrict__ sorted,    // [E]
    const unsigned short* __restrict__ Wt,  // [3][8][32][128] fp16 swizzled-k
    const float* __restrict__ W_rel,     // [R]
    float* __restrict__ out,             // [N,32]; holds self_term on entry
    int N)
{
    __shared__ unsigned int zh[NB_ * R_ * 64];   // 32 KB: z fp16 -> q/k/v -> delta
    __shared__ int   sortbuf[2 * EMAX_];         // 4 KB: ebuf+sbuf -> psi_l
    __shared__ float ai[NB_][32];                // 2 KB
    __shared__ int   bstart[128];                // 512 B
    __shared__ int   bcur[128];                  // 512 B; mskl overlay
    __shared__ int   wtot[2];

    int* ebuf = sortbuf;
    int* sbuf = sortbuf + EMAX_;

    const int tid = threadIdx.x;
    const int n0  = blockIdx.x * NB_;

    const int e0 = offsets[blockIdx.x];
    const int e1 = offsets[blockIdx.x + 1];
    const int ecount_raw = e1 - e0;
    const int ecount = (ecount_raw < EMAX_) ? ecount_raw : EMAX_;

    // init zh = self_node (fp16 swizzled), load AI, stage edges
    {
        const unsigned int* sn_u = (const unsigned int*)sn16;
        for (int u = tid; u < NB_ * R_ * 64; u += 512) {
            int n  = u >> 9;
            int mu = u & 511;
            zh[u] = (n0 + n < N) ? sn_u[(size_t)(n0 + n) * 64 + (mu & 63)] : 0u;
        }
        int nl = tid >> 5, rh = tid & 31;
        ai[nl][rh] = (n0 + nl < N) ? AI[(size_t)(n0 + nl) * 32 + rh] : 0.f;
        if (tid < 128) bstart[tid] = 0;
        for (int i = tid; i < ecount; i += 512) ebuf[i] = sorted[e0 + i];
    }
    __syncthreads();

    // counting sort by key = nl*8 + r (128 buckets)
    for (int i = tid; i < ecount; i += 512) {
        int pk = ebuf[i];
        int key = (((pk >> 20) & 15) << 3) | ((pk >> 17) & 7);
        atomicAdd(&bstart[key], 1);
    }
    __syncthreads();
    int scan_s = 0, scan_v = 0;
    if (tid < 128) {
        scan_v = bstart[tid];
        scan_s = scan_v;
        #pragma unroll
        for (int d = 1; d < 64; d <<= 1) {
            int t = __shfl_up(scan_s, d, 64);
            if ((tid & 63) >= d) scan_s += t;
        }
        if ((tid & 63) == 63) wtot[tid >> 6] = scan_s;
    }
    __syncthreads();
    if (tid < 128) {
        int add  = (tid >= 64) ? wtot[0] : 0;
        int excl = scan_s - scan_v + add;
        bstart[tid] = excl;
        bcur[tid]   = excl;
    }
    __syncthreads();
    for (int i = tid; i < ecount; i += 512) {
        int pk = ebuf[i];
        int key = (((pk >> 20) & 15) << 3) | ((pk >> 17) & 7);
        int pos = atomicAdd(&bcur[key], 1);
        sbuf[pos] = pk;
    }
    __syncthreads();

    // ---- walk: half-wave = one node; register-finalized z per (n,r) run.
    //      Uniform 4-wide software pipeline: prefetch slots are CLAMPED to
    //      t_-1 (no scalar-remainder path), temps+sched_barrier pin the 8
    //      gather loads BEFORE the compute of the previous 4 edges so they
    //      stay in flight for a full iteration (~4 edge-computes of cover).
    {
        const int nl = tid >> 5;          // 0..15
        const int l  = tid & 31;
        int s_ = bstart[nl * 8];
        int t_ = (nl == 15) ? ecount : bstart[nl * 8 + 8];

        ushort4 snv = make_ushort4(0, 0, 0, 0);
        if (n0 + nl < N)
            snv = *(const ushort4*)(sn16 + (size_t)(n0 + nl) * 128 + l * 4);
        float sn0 = h2f(snv.x), sn1 = h2f(snv.y), sn2 = h2f(snv.z), sn3 = h2f(snv.w);

        int cur_r = -1;
        float acc0 = 0.f, acc1 = 0.f, acc2 = 0.f, acc3 = 0.f;
        float dn0 = 0.f, dn1 = 0.f, dn2 = 0.f, dn3 = 0.f;

#define ISSUE_EDGE(idxe, pkv, hvv, ajv) {                                      \
        int idx_ = (idxe); if (idx_ > t_ - 1) idx_ = t_ - 1;                   \
        int p_ = sbuf[idx_]; pkv = p_;                                         \
        int src_ = p_ & 0x1FFFF; int rr_ = (p_ >> 17) & 7;                     \
        hvv = *(const ushort4*)(hjb + (size_t)src_ * 128 + l * 4);             \
        ajv = *(const float4*)(AJ + (size_t)src_ * 32 + rr_ * 4); }

#define FINALIZE_RUN() {                                                       \
        float i0 = 1.f / (dn0 + 1e-16f), i1 = 1.f / (dn1 + 1e-16f);            \
        float i2 = 1.f / (dn2 + 1e-16f), i3 = 1.f / (dn3 + 1e-16f);            \
        unsigned lo = pack2(acc0 * i0 + sn0, acc1 * i1 + sn1);                 \
        unsigned hi = pack2(acc2 * i2 + sn2, acc3 * i3 + sn3);                 \
        unsigned int* zp = &zh[((nl * 8 + cur_r) << 6) + l * 2];               \
        zp[0] = lo; zp[1] = hi; }

#define COMPUTE_EDGE(d, p, hv, aj)                                             \
        if (base + (d) < t_) {                                                 \
            int rr = ((p) >> 17) & 7;                                          \
            if (rr != cur_r) {                                                 \
                if (cur_r >= 0) { FINALIZE_RUN() }                             \
                cur_r = rr;                                                    \
                acc0 = acc1 = acc2 = acc3 = 0.f;                               \
                dn0 = dn1 = dn2 = dn3 = 0.f;                                   \
            }                                                                  \
            float4 aiv = *(const float4*)&ai[nl][rr * 4];                      \
            float a0 = aiv.x + (aj).x; a0 = (a0 > 0.f) ? a0 : 0.2f * a0;       \
            float a1 = aiv.y + (aj).y; a1 = (a1 > 0.f) ? a1 : 0.2f * a1;       \
            float a2 = aiv.z + (aj).z; a2 = (a2 > 0.f) ? a2 : 0.2f * a2;       \
            float a3 = aiv.w + (aj).w; a3 = (a3 > 0.f) ? a3 : 0.2f * a3;       \
            float x0 = __expf(a0), x1 = __expf(a1);                            \
            float x2 = __expf(a2), x3 = __expf(a3);                            \
            dn0 += x0; dn1 += x1; dn2 += x2; dn3 += x3;                        \
            acc0 += x0 * h2f((hv).x); acc1 += x1 * h2f((hv).y);                \
            acc2 += x2 * h2f((hv).z); acc3 += x3 * h2f((hv).w);                \
        }

        if (s_ < t_) {
            int pk0, pk1, pk2, pk3;
            ushort4 hv0, hv1, hv2, hv3;
            float4 aj0, aj1, aj2, aj3;
            ISSUE_EDGE(s_ + 0, pk0, hv0, aj0);
            ISSUE_EDGE(s_ + 1, pk1, hv1, aj1);
            ISSUE_EDGE(s_ + 2, pk2, hv2, aj2);
            ISSUE_EDGE(s_ + 3, pk3, hv3, aj3);
            for (int base = s_; base < t_; base += 4) {
                int     tpk0 = pk0, tpk1 = pk1, tpk2 = pk2, tpk3 = pk3;
                ushort4 thv0 = hv0, thv1 = hv1, thv2 = hv2, thv3 = hv3;
                float4  taj0 = aj0, taj1 = aj1, taj2 = aj2, taj3 = aj3;
                ISSUE_EDGE(base + 4, pk0, hv0, aj0);
                ISSUE_EDGE(base + 5, pk1, hv1, aj1);
                ISSUE_EDGE(base + 6, pk2, hv2, aj2);
                ISSUE_EDGE(base + 7, pk3, hv3, aj3);
                __builtin_amdgcn_sched_barrier(0);
                COMPUTE_EDGE(0, tpk0, thv0, taj0);
                COMPUTE_EDGE(1, tpk1, thv1, taj1);
                COMPUTE_EDGE(2, tpk2, thv2, taj2);
                COMPUTE_EDGE(3, tpk3, thv3, taj3);
            }
            if (cur_r >= 0) { FINALIZE_RUN() }
        }
#undef ISSUE_EDGE
#undef FINALIZE_RUN
#undef COMPUTE_EDGE
    }
    __syncthreads();

    // ---- q,k,v via fp16 dot2: wave w = relation; half-waves 8 nodes each
    const int w    = tid >> 6;          // 0..7 == relation
    const int lane = tid & 63;
    const int c    = lane & 31;
    const int nh   = lane >> 5;         // node half: 0 -> 0..7, 1 -> 8..15
    const int nbase = nh * 8;

    float qa[8], ka[8], va[8];
    #pragma unroll
    for (int n = 0; n < 8; ++n) { qa[n] = 0.f; ka[n] = 0.f; va[n] = 0.f; }
    {
        const unsigned int* wtu = (const unsigned int*)Wt;
        const unsigned int* wq = wtu +                 ((w * 32 + c) << 6);
        const unsigned int* wk = wtu + (8 * 32 * 64) + ((w * 32 + c) << 6);
        const unsigned int* wv = wtu + (16 * 32 * 64) + ((w * 32 + c) << 6);
        for (int mc = 0; mc < 64; mc += 4) {
            uint4 q4 = *(const uint4*)(wq + mc);
            uint4 k4 = *(const uint4*)(wk + mc);
            uint4 v4 = *(const uint4*)(wv + mc);
            #pragma unroll
            for (int n = 0; n < 8; ++n) {
                uint4 z = *(const uint4*)&zh[(((nbase + n) * 8 + w) << 6) + mc];
                float a;
                a = qa[n]; a = dot2(z.x, q4.x, a); a = dot2(z.y, q4.y, a);
                a = dot2(z.z, q4.z, a); a = dot2(z.w, q4.w, a); qa[n] = a;
                a = ka[n]; a = dot2(z.x, k4.x, a); a = dot2(z.y, k4.y, a);
                a = dot2(z.z, k4.z, a); a = dot2(z.w, k4.w, a); ka[n] = a;
                a = va[n]; a = dot2(z.x, v4.x, a); a = dot2(z.y, v4.y, a);
                a = dot2(z.z, v4.z, a); a = dot2(z.w, v4.w, a); va[n] = a;
            }
        }
    }
    __syncthreads();   // zh reads done -> overlay q/k/v fp16 onto zh
    unsigned short* qh = (unsigned short*)zh;       // [n][r][32] fp16, 8 KB
    unsigned short* kh = qh + 4096;                 // 8 KB
    unsigned short* vh = qh + 8192;                 // 8 KB
    float* psi_l = (float*)sortbuf;                 // 4 KB (sort done)
    #pragma unroll
    for (int n = 0; n < 8; ++n) {
        int base = ((nbase + n) * 8 + w) * 32 + c;
        qh[base] = f2h(qa[n]);
        kh[base] = f2h(ka[n]);
        vh[base] = f2h(va[n]);
    }
    __syncthreads();

    // ---- psi[n][rr][ss] = <q[n,rr], k[n,ss]> (fp16 dot2) ----
    for (int idx = tid; idx < NB_ * 64; idx += 512) {
        int n = idx >> 6, rr = (idx >> 3) & 7, ss = idx & 7;
        const unsigned int* q4 = (const unsigned int*)(qh + (n * 8 + rr) * 32);
        const unsigned int* k4 = (const unsigned int*)(kh + (n * 8 + ss) * 32);
        float p = 0.f;
        #pragma unroll
        for (int c2 = 0; c2 < 16; c2 += 4) {
            uint4 a = *(const uint4*)(q4 + c2);
            uint4 b = *(const uint4*)(k4 + c2);
            p = dot2(a.x, b.x, p); p = dot2(a.y, b.y, p);
            p = dot2(a.z, b.z, p); p = dot2(a.w, b.w, p);
        }
        psi_l[idx] = p;
    }
    __syncthreads();
    if (tid < NB_ * 8) {
        float* row = &psi_l[tid * 8];
        float m = -INFINITY;
        #pragma unroll
        for (int s = 0; s < 8; ++s) m = fmaxf(m, row[s]);
        float sum = 0.f;
        #pragma unroll
        for (int s = 0; s < 8; ++s) { float e = __expf(row[s] - m); row[s] = e; sum += e; }
        float inv = 1.f / sum;
        #pragma unroll
        for (int s = 0; s < 8; ++s) row[s] *= inv;
    }
    __syncthreads();

    // ---- delta[n][r][c] = sum_s psi * v (wave w = relation) ----
    float dl[8];
    #pragma unroll
    for (int n = 0; n < 8; ++n) dl[n] = 0.f;
    #pragma unroll
    for (int s = 0; s < 8; ++s) {
        #pragma unroll
        for (int n = 0; n < 8; ++n) {
            float vv = h2f(vh[((nbase + n) * 8 + s) * 32 + c]);
            dl[n] += psi_l[(nbase + n) * 64 + w * 8 + s] * vv;
        }
    }
    __syncthreads();   // q/k reads done -> overlay delta fp32 (16 KB, vh safe)
    float* dbuf = (float*)zh;          // [n][r][32] fp32
    float* mskl = (float*)bcur;        // bcur dead after sort
    #pragma unroll
    for (int n = 0; n < 8; ++n)
        dbuf[((nbase + n) * 8 + w) * 32 + c] = dl[n];
    __syncthreads();

    // ---- mask[n][r] = (sum_c delta != 0) ----
    if (tid < NB_ * 8) {
        int n = tid >> 3, rr = tid & 7;
        float s = 0.f;
        #pragma unroll
        for (int cc = 0; cc < 32; ++cc) s += dbuf[(n * 8 + rr) * 32 + cc];
        mskl[tid] = (s != 0.f) ? 1.f : 0.f;
    }
    __syncthreads();

    // ---- out[n] = sum_r (delta + self_term*mask) * W_rel[r] ----
    {
        int n = tid >> 5, cc = tid & 31;   // 512 = 16 nodes x 32 cols
        if (n0 + n < N) {
            float st = out[(size_t)(n0 + n) * 32 + cc];
            float o = 0.f;
            #pragma unroll
            for (int rr = 0; rr < 8; ++rr)
                o += (dbuf[(n * 8 + rr) * 32 + cc] + st * mskl[n * 8 + rr]) * W_rel[rr];
            out[(size_t)(n0 + n) * 32 + cc] = o;
        }
    }
}

// -------------------------------------------------------------------------
extern "C" void kernel_launch(void* const* d_in, const int* in_sizes, int n_in,
                              void* d_out, int out_size, void* d_ws, size_t ws_size,
                              hipStream_t stream)
{
    const float* x      = (const float*)d_in[0];
    const int*   ei     = (const int*)  d_in[1];   // [2,E]
    const int*   et     = (const int*)  d_in[2];   // [E]
    const float* Wj     = (const float*)d_in[3];
    const float* Wi     = (const float*)d_in[4];
    const float* natt   = (const float*)d_in[5];
    const float* W_q    = (const float*)d_in[6];
    const float* W_k    = (const float*)d_in[7];
    const float* W_v    = (const float*)d_in[8];
    const float* W_self = (const float*)d_in[9];
    const float* W_sn   = (const float*)d_in[10];
    const float* W_rel  = (const float*)d_in[11];
    float* out = (float*)d_out;

    const int N = in_sizes[0] / INF_;
    const int E = in_sizes[2];
    const int G = (N + NB_ - 1) / NB_;   // 16-node groups

    // workspace layout (~42 MB)
    float* ws        = (float*)d_ws;
    float* AI        = ws;                               // N*32
    float* AJ        = AI + (size_t)N * 32;              // N*32
    unsigned short* hjb  = (unsigned short*)(AJ + (size_t)N * 32); // N*128 fp16
    unsigned short* sn16 = hjb + (size_t)N * 128;        // N*128 fp16
    unsigned short* Wt   = sn16 + (size_t)N * 128;       // 98304 fp16
    unsigned* Wp     = (unsigned*)(Wt + 98304);          // 352*64 uint
    int*   counts    = (int*)(Wp + 352 * 64);            // G+1
    int*   offsets   = counts + (G + 1);                 // G+1
    int*   cursor    = offsets + (G + 1);                // G
    int*   sorted    = cursor + G;                       // E

    // ---- prep (Wt + Wp incl. inline M + zero counts) ----
    const int prep_total = 98304 + 352 * 64 + (G + 1);
    prep_all<<<(prep_total + 255) / 256, 256, 0, stream>>>(
        W_q, W_k, W_v, Wj, Wi, W_sn, W_self, natt, Wt, Wp, counts, G);

    // ---- CSR build ----
    count_edges<<<(E + 255) / 256, 256, 0, stream>>>(ei, counts, E);
    scan_offsets<<<1, 1024, 0, stream>>>(counts, offsets, cursor, G);
    scatter_edges<<<(E + 255) / 256, 256, 0, stream>>>(ei, et, cursor, sorted, E);

    // ---- node feature GEMMs ----
    fused_gemm<<<(N + 31) / 32, 256, 0, stream>>>(
        x, Wp, hjb, sn16, out, AI, AJ, N);

    // ---- fused edge aggregation + tail ----
    edge_tail<<<G, 512, 0, stream>>>(
        hjb, sn16, AJ, AI, offsets, sorted, Wt, W_rel, out, N);
}

// Round 2
// 630.532 us; speedup vs baseline: 1.0052x; 1.0029x over previous
//
#include <hip/hip_runtime.h>
#include <hip/hip_fp16.h>
#include <math.h>

constexpr int INF_ = 128;  // IN
constexpr int H_   = 4;
constexpr int C_   = 32;
constexpr int R_   = 8;
constexpr int NB_  = 16;   // nodes per block
constexpr int EMAX_ = 512; // staged edges per block (mean ~205, +21 sigma)

typedef _Float16 half2_t __attribute__((ext_vector_type(2)));

__device__ __forceinline__ unsigned short f2h(float f) {
    return __half_as_ushort(__float2half(f));
}
__device__ __forceinline__ float h2f(unsigned short u) {
    return __half2float(__ushort_as_half(u));
}
__device__ __forceinline__ unsigned pack2(float a, float b) {
    return (unsigned)f2h(a) | ((unsigned)f2h(b) << 16);
}
__device__ __forceinline__ float dot2(unsigned a, unsigned b, float c) {
#if __has_builtin(__builtin_amdgcn_fdot2)
    return __builtin_amdgcn_fdot2(__builtin_bit_cast(half2_t, a),
                                  __builtin_bit_cast(half2_t, b), c, false);
#else
    c += h2f((unsigned short)(a & 0xFFFF)) * h2f((unsigned short)(b & 0xFFFF));
    c += h2f((unsigned short)(a >> 16))    * h2f((unsigned short)(b >> 16));
    return c;
#endif
}

// -------------------------------------------------------------------------
// CSR build at 16-node GROUP granularity.
// -------------------------------------------------------------------------
__global__ __launch_bounds__(256) void count_edges(
    const int* __restrict__ ei, int* __restrict__ counts, int E)
{
    int e = blockIdx.x * 256 + threadIdx.x;
    if (e >= E) return;
    int dst = ei[E + e];
    atomicAdd(&counts[dst >> 4], 1);
}

// writes offsets[0..G] AND cursor[0..G) (= offsets copy)
__global__ __launch_bounds__(1024) void scan_offsets(
    const int* __restrict__ counts, int* __restrict__ offsets,
    int* __restrict__ cursor, int G)
{
    __shared__ int wsum[16];
    __shared__ int chunk_tot;
    const int tid  = threadIdx.x;
    const int lane = tid & 63;
    const int wid  = tid >> 6;
    int carry = 0;
    for (int base = 0; base < G; base += 1024) {
        int i = base + tid;
        int v = (i < G) ? counts[i] : 0;
        int s = v;
        #pragma unroll
        for (int d = 1; d < 64; d <<= 1) {
            int t = __shfl_up(s, d, 64);
            if (lane >= d) s += t;
        }
        if (lane == 63) wsum[wid] = s;
        __syncthreads();
        if (tid == 0) {
            int acc = 0;
            #pragma unroll
            for (int w = 0; w < 16; ++w) { int t = wsum[w]; wsum[w] = acc; acc += t; }
            chunk_tot = acc;
        }
        __syncthreads();
        int excl = carry + wsum[wid] + (s - v);
        if (i < G) { offsets[i] = excl; cursor[i] = excl; }
        carry += chunk_tot;
        __syncthreads();
    }
    if (tid == 0) offsets[G] = carry;
}

// packed: src | r<<17 | (dst&15)<<20
__global__ __launch_bounds__(256) void scatter_edges(
    const int* __restrict__ ei, const int* __restrict__ et,
    int* __restrict__ cursor, int* __restrict__ sorted, int E)
{
    int e = blockIdx.x * 256 + threadIdx.x;
    if (e >= E) return;
    int src = ei[e];
    int dst = ei[E + e];
    int r   = et[e];
    int pos = atomicAdd(&cursor[dst >> 4], 1);
    sorted[pos] = src | (r << 17) | ((dst & 15) << 20);
}

// -------------------------------------------------------------------------
// prep_all: one kernel, three disjoint jobs.
//  A [0, 98304): Wt fp16 qkv transpose, swizzled-k order.
//  B [98304, 98304+22528): Wp = 352-col combined node-GEMM weight, fp16
//     k-pair packed; cols 288..351 compute M_i/M_j INLINE from Wi/Wj+natt.
//  C: zero counts[0..G].
// -------------------------------------------------------------------------
__global__ __launch_bounds__(256) void prep_all(
    const float* __restrict__ W_q, const float* __restrict__ W_k,
    const float* __restrict__ W_v,
    const float* __restrict__ Wj,  const float* __restrict__ Wi,
    const float* __restrict__ Wsn, const float* __restrict__ Wself,
    const float* __restrict__ natt,
    unsigned short* __restrict__ Wt,   // [3][8][32][128] fp16
    unsigned* __restrict__ Wp,         // [352][64] fp16 pairs
    int* __restrict__ counts, int G)
{
    int idx = blockIdx.x * 256 + threadIdx.x;
    if (idx < 98304) {
        int mat = idx >> 15;
        int rem = idx & 32767;
        int r   = rem >> 12;
        int c   = (rem >> 7) & 31;
        int m   = rem & 127;
        int k   = (m & 3) * 32 + (m >> 2);
        const float* W = (mat == 0) ? W_q : (mat == 1) ? W_k : W_v;
        Wt[idx] = f2h(W[r * 4096 + k * 32 + c]);
        return;
    }
    int j = idx - 98304;
    if (j < 352 * 64) {
        int col = j >> 6;
        int m   = j & 63;
        float w0, w1;
        if (col < 288) {
            const float* W; int wcol, wstride;
            if (col < 128)      { W = Wj;    wcol = col;       wstride = 128; }
            else if (col < 256) { W = Wsn;   wcol = col - 128; wstride = 128; }
            else                { W = Wself; wcol = col - 256; wstride = 32;  }
            w0 = W[(2 * m)     * wstride + wcol];
            w1 = W[(2 * m + 1) * wstride + wcol];
        } else {
            // inline M_i (cols 288..319) / M_j (320..351):
            // M(d, c) = sum_cc W[d*128 + h*32 + cc] * natt[c*64 + off + cc]
            int which = (col >= 320);
            int c  = col - (which ? 320 : 288);   // 0..31
            int h  = c & 3;
            const float* W   = which ? Wj : Wi;
            const float* att = natt + c * 64 + (which ? 32 : 0);
            float a0 = 0.f, a1 = 0.f;
            const float* w0p = W + (2 * m)     * 128 + h * 32;
            const float* w1p = W + (2 * m + 1) * 128 + h * 32;
            #pragma unroll
            for (int cc = 0; cc < 32; ++cc) {
                float av = att[cc];
                a0 += w0p[cc] * av;
                a1 += w1p[cc] * av;
            }
            w0 = a0; w1 = a1;
        }
        Wp[j] = pack2(w0, w1);
        return;
    }
    j -= 352 * 64;
    if (j <= G) counts[j] = 0;
}

// -------------------------------------------------------------------------
// Fused node GEMMs — fp16 dot2, x tile read ONCE (fp16 in LDS).
//   cg 0..3: h_j fp16 swizzled; cg 4..7: self_node fp16 swizzled;
//   cg 8: self_term fp32 (d_out); cg 9: AI; cg 10: AJ.
// -------------------------------------------------------------------------
__global__ __launch_bounds__(256) void fused_gemm(
    const float* __restrict__ x,
    const unsigned* __restrict__ Wp,    // [352][64] fp16 pairs
    unsigned short* __restrict__ hjb,   // [N*128] fp16 swizzled
    unsigned short* __restrict__ sn16,  // [N*128] fp16 swizzled
    float* __restrict__ self_term,      // = d_out
    float* __restrict__ AI,
    float* __restrict__ AJ,
    int N)
{
    __shared__ unsigned xs[32][64];     // 8 KB fp16 pairs
    const int n0  = blockIdx.x * 32;
    const int tid = threadIdx.x;

    #pragma unroll
    for (int j = 0; j < 4; ++j) {
        int f4   = tid + 256 * j;
        int row  = f4 >> 5;
        int col4 = f4 & 31;
        float4 v = make_float4(0.f, 0.f, 0.f, 0.f);
        if (n0 + row < N)
            v = *(const float4*)(x + (size_t)(n0 + row) * 128 + col4 * 4);
        xs[row][col4 * 2]     = pack2(v.x, v.y);
        xs[row][col4 * 2 + 1] = pack2(v.z, v.w);
    }
    __syncthreads();

    const int c_local = tid & 31;
    const int n_base  = tid >> 5;
    const bool ok0 = (n0 + n_base      < N);
    const bool ok1 = (n0 + n_base +  8 < N);
    const bool ok2 = (n0 + n_base + 16 < N);
    const bool ok3 = (n0 + n_base + 24 < N);

    for (int cg = 0; cg < 11; ++cg) {
        const int col = cg * 32 + c_local;
        const unsigned* wp = Wp + col * 64;

        float acc0 = 0.f, acc1 = 0.f, acc2 = 0.f, acc3 = 0.f;
        for (int m = 0; m < 64; m += 4) {
            uint4 w  = *(const uint4*)(wp + m);
            uint4 x0 = *(const uint4*)&xs[n_base     ][m];
            uint4 x1 = *(const uint4*)&xs[n_base +  8][m];
            uint4 x2 = *(const uint4*)&xs[n_base + 16][m];
            uint4 x3 = *(const uint4*)&xs[n_base + 24][m];
            acc0 = dot2(x0.x, w.x, acc0); acc0 = dot2(x0.y, w.y, acc0);
            acc0 = dot2(x0.z, w.z, acc0); acc0 = dot2(x0.w, w.w, acc0);
            acc1 = dot2(x1.x, w.x, acc1); acc1 = dot2(x1.y, w.y, acc1);
            acc1 = dot2(x1.z, w.z, acc1); acc1 = dot2(x1.w, w.w, acc1);
            acc2 = dot2(x2.x, w.x, acc2); acc2 = dot2(x2.y, w.y, acc2);
            acc2 = dot2(x2.z, w.z, acc2); acc2 = dot2(x2.w, w.w, acc2);
            acc3 = dot2(x3.x, w.x, acc3); acc3 = dot2(x3.y, w.y, acc3);
            acc3 = dot2(x3.z, w.z, acc3); acc3 = dot2(x3.w, w.w, acc3);
        }

        if (cg < 4) {
            int so = c_local * 4 + cg;
            if (ok0) hjb[(size_t)(n0 + n_base     ) * 128 + so] = f2h(acc0);
            if (ok1) hjb[(size_t)(n0 + n_base +  8) * 128 + so] = f2h(acc1);
            if (ok2) hjb[(size_t)(n0 + n_base + 16) * 128 + so] = f2h(acc2);
            if (ok3) hjb[(size_t)(n0 + n_base + 24) * 128 + so] = f2h(acc3);
        } else if (cg < 8) {
            int so = c_local * 4 + (cg - 4);
            if (ok0) sn16[(size_t)(n0 + n_base     ) * 128 + so] = f2h(acc0);
            if (ok1) sn16[(size_t)(n0 + n_base +  8) * 128 + so] = f2h(acc1);
            if (ok2) sn16[(size_t)(n0 + n_base + 16) * 128 + so] = f2h(acc2);
            if (ok3) sn16[(size_t)(n0 + n_base + 24) * 128 + so] = f2h(acc3);
        } else {
            float* outb = (cg == 8) ? self_term : (cg == 9) ? AI : AJ;
            if (ok0) outb[(size_t)(n0 + n_base     ) * 32 + c_local] = acc0;
            if (ok1) outb[(size_t)(n0 + n_base +  8) * 32 + c_local] = acc1;
            if (ok2) outb[(size_t)(n0 + n_base + 16) * 32 + c_local] = acc2;
            if (ok3) outb[(size_t)(n0 + n_base + 24) * 32 + c_local] = acc3;
        }
    }
}

// -------------------------------------------------------------------------
// FUSED edge aggregation + tail, 512 threads / 16 nodes per block.
// LDS ~39.9 KB; walk is a BRANCHLESS 4-deep software pipeline:
//  - slots past t_ are clamped to edge t_-1 (same relation as cur_r, so no
//    spurious run switch) and their exp-contribution is killed via -INF;
//  - asm memory fence between issue group and compute group prevents
//    MachineSink/scheduler from re-serializing the gathers (round-0 failure:
//    conditional slot guards let the loads sink to their uses, VGPR stayed 48).
// zh reused for q/k/v (fp16) then delta (fp32); sortbuf reused for psi;
// bcur reused for mskl.
// -------------------------------------------------------------------------
__global__ __launch_bounds__(512, 2) void edge_tail(
    const unsigned short* __restrict__ hjb,  // [N*128] fp16 swizzled
    const unsigned short* __restrict__ sn16, // [N*128] fp16 swizzled
    const float* __restrict__ AJ,        // [N,32]
    const float* __restrict__ AI,        // [N,32]
    const int*   __restrict__ offsets,   // [G+1]
    const int*   __restrict__ sorted,    // [E]
    const unsigned short* __restrict__ Wt,  // [3][8][32][128] fp16 swizzled-k
    const float* __restrict__ W_rel,     // [R]
    float* __restrict__ out,             // [N,32]; holds self_term on entry
    int N)
{
    __shared__ unsigned int zh[NB_ * R_ * 64];   // 32 KB: z fp16 -> q/k/v -> delta
    __shared__ int   sortbuf[2 * EMAX_];         // 4 KB: ebuf+sbuf -> psi_l
    __shared__ float ai[NB_][32];                // 2 KB
    __shared__ int   bstart[128];                // 512 B
    __shared__ int   bcur[128];                  // 512 B; mskl overlay
    __shared__ int   wtot[2];

    int* ebuf = sortbuf;
    int* sbuf = sortbuf + EMAX_;

    const int tid = threadIdx.x;
    const int n0  = blockIdx.x * NB_;

    const int e0 = offsets[blockIdx.x];
    const int e1 = offsets[blockIdx.x + 1];
    const int ecount_raw = e1 - e0;
    const int ecount = (ecount_raw < EMAX_) ? ecount_raw : EMAX_;

    // init zh = self_node (fp16 swizzled), load AI, stage edges
    {
        const unsigned int* sn_u = (const unsigned int*)sn16;
        for (int u = tid; u < NB_ * R_ * 64; u += 512) {
            int n  = u >> 9;
            int mu = u & 511;
            zh[u] = (n0 + n < N) ? sn_u[(size_t)(n0 + n) * 64 + (mu & 63)] : 0u;
        }
        int nl = tid >> 5, rh = tid & 31;
        ai[nl][rh] = (n0 + nl < N) ? AI[(size_t)(n0 + nl) * 32 + rh] : 0.f;
        if (tid < 128) bstart[tid] = 0;
        for (int i = tid; i < ecount; i += 512) ebuf[i] = sorted[e0 + i];
    }
    __syncthreads();

    // counting sort by key = nl*8 + r (128 buckets)
    for (int i = tid; i < ecount; i += 512) {
        int pk = ebuf[i];
        int key = (((pk >> 20) & 15) << 3) | ((pk >> 17) & 7);
        atomicAdd(&bstart[key], 1);
    }
    __syncthreads();
    int scan_s = 0, scan_v = 0;
    if (tid < 128) {
        scan_v = bstart[tid];
        scan_s = scan_v;
        #pragma unroll
        for (int d = 1; d < 64; d <<= 1) {
            int t = __shfl_up(scan_s, d, 64);
            if ((tid & 63) >= d) scan_s += t;
        }
        if ((tid & 63) == 63) wtot[tid >> 6] = scan_s;
    }
    __syncthreads();
    if (tid < 128) {
        int add  = (tid >= 64) ? wtot[0] : 0;
        int excl = scan_s - scan_v + add;
        bstart[tid] = excl;
        bcur[tid]   = excl;
    }
    __syncthreads();
    for (int i = tid; i < ecount; i += 512) {
        int pk = ebuf[i];
        int key = (((pk >> 20) & 15) << 3) | ((pk >> 17) & 7);
        int pos = atomicAdd(&bcur[key], 1);
        sbuf[pos] = pk;
    }
    __syncthreads();

    // ---- walk: half-wave = one node; register-finalized z per (n,r) run.
    {
        const int nl = tid >> 5;          // 0..15
        const int l  = tid & 31;
        int s_ = bstart[nl * 8];
        int t_ = (nl == 15) ? ecount : bstart[nl * 8 + 8];

        ushort4 snv = make_ushort4(0, 0, 0, 0);
        if (n0 + nl < N)
            snv = *(const ushort4*)(sn16 + (size_t)(n0 + nl) * 128 + l * 4);
        float sn0 = h2f(snv.x), sn1 = h2f(snv.y), sn2 = h2f(snv.z), sn3 = h2f(snv.w);

        int cur_r = -1;
        float acc0 = 0.f, acc1 = 0.f, acc2 = 0.f, acc3 = 0.f;
        float dn0 = 0.f, dn1 = 0.f, dn2 = 0.f, dn3 = 0.f;

#define ISSUE_EDGE(idxe, pkv, hvv, ajv) {                                      \
        int idx_ = (idxe); idx_ = (idx_ < tlast) ? idx_ : tlast;               \
        int p_ = sbuf[idx_]; (pkv) = p_;                                       \
        unsigned src_ = (unsigned)(p_ & 0x1FFFF);                              \
        unsigned rr_  = (unsigned)((p_ >> 17) & 7);                            \
        (hvv) = *(const ushort4*)(hjb + (src_ << 7) + ((unsigned)l << 2));     \
        (ajv) = *(const float4*)(AJ + (src_ << 5) + (rr_ << 2)); }

#define FINALIZE_RUN() {                                                       \
        float i0 = 1.f / (dn0 + 1e-16f), i1 = 1.f / (dn1 + 1e-16f);            \
        float i2 = 1.f / (dn2 + 1e-16f), i3 = 1.f / (dn3 + 1e-16f);            \
        unsigned lo = pack2(acc0 * i0 + sn0, acc1 * i1 + sn1);                 \
        unsigned hi = pack2(acc2 * i2 + sn2, acc3 * i3 + sn3);                 \
        unsigned int* zp = &zh[((nl * 8 + cur_r) << 6) + l * 2];               \
        zp[0] = lo; zp[1] = hi; }

// Branchless validity: slot d past t_ re-reads edge t_-1 (same relation as
// cur_r -> no spurious finalize); am = -INF kills its exp contribution.
#define COMPUTE_EDGE(d, p, hv, aj) {                                           \
        int rr = ((p) >> 17) & 7;                                              \
        if (rr != cur_r) {                                                     \
            if (cur_r >= 0) { FINALIZE_RUN() }                                 \
            cur_r = rr;                                                        \
            acc0 = acc1 = acc2 = acc3 = 0.f;                                   \
            dn0 = dn1 = dn2 = dn3 = 0.f;                                       \
        }                                                                      \
        float am = (base + (d) < t_) ? 0.f : -INFINITY;                        \
        float4 aiv = *(const float4*)&ai[nl][rr * 4];                          \
        float a0 = aiv.x + (aj).x; a0 = (a0 > 0.f) ? a0 : 0.2f * a0; a0 += am; \
        float a1 = aiv.y + (aj).y; a1 = (a1 > 0.f) ? a1 : 0.2f * a1; a1 += am; \
        float a2 = aiv.z + (aj).z; a2 = (a2 > 0.f) ? a2 : 0.2f * a2; a2 += am; \
        float a3 = aiv.w + (aj).w; a3 = (a3 > 0.f) ? a3 : 0.2f * a3; a3 += am; \
        float x0 = __expf(a0), x1 = __expf(a1);                                \
        float x2 = __expf(a2), x3 = __expf(a3);                                \
        dn0 += x0; dn1 += x1; dn2 += x2; dn3 += x3;                            \
        acc0 += x0 * h2f((hv).x); acc1 += x1 * h2f((hv).y);                    \
        acc2 += x2 * h2f((hv).z); acc3 += x3 * h2f((hv).w);                    \
    }

        if (s_ < t_) {
            const int tlast = t_ - 1;
            int pk0, pk1, pk2, pk3;
            ushort4 hv0, hv1, hv2, hv3;
            float4 aj0, aj1, aj2, aj3;
            ISSUE_EDGE(s_ + 0, pk0, hv0, aj0);
            ISSUE_EDGE(s_ + 1, pk1, hv1, aj1);
            ISSUE_EDGE(s_ + 2, pk2, hv2, aj2);
            ISSUE_EDGE(s_ + 3, pk3, hv3, aj3);
            for (int base = s_; base < t_; base += 4) {
                int     tpk0 = pk0, tpk1 = pk1, tpk2 = pk2, tpk3 = pk3;
                ushort4 thv0 = hv0, thv1 = hv1, thv2 = hv2, thv3 = hv3;
                float4  taj0 = aj0, taj1 = aj1, taj2 = aj2, taj3 = aj3;
                ISSUE_EDGE(base + 4, pk0, hv0, aj0);
                ISSUE_EDGE(base + 5, pk1, hv1, aj1);
                ISSUE_EDGE(base + 6, pk2, hv2, aj2);
                ISSUE_EDGE(base + 7, pk3, hv3, aj3);
                asm volatile("" ::: "memory");   // pin: loads may not sink below
                COMPUTE_EDGE(0, tpk0, thv0, taj0);
                COMPUTE_EDGE(1, tpk1, thv1, taj1);
                COMPUTE_EDGE(2, tpk2, thv2, taj2);
                COMPUTE_EDGE(3, tpk3, thv3, taj3);
            }
            if (cur_r >= 0) { FINALIZE_RUN() }
        }
#undef ISSUE_EDGE
#undef FINALIZE_RUN
#undef COMPUTE_EDGE
    }
    __syncthreads();

    // ---- q,k,v via fp16 dot2: wave w = relation; half-waves 8 nodes each
    const int w    = tid >> 6;          // 0..7 == relation
    const int lane = tid & 63;
    const int c    = lane & 31;
    const int nh   = lane >> 5;         // node half: 0 -> 0..7, 1 -> 8..15
    const int nbase = nh * 8;

    float qa[8], ka[8], va[8];
    #pragma unroll
    for (int n = 0; n < 8; ++n) { qa[n] = 0.f; ka[n] = 0.f; va[n] = 0.f; }
    {
        const unsigned int* wtu = (const unsigned int*)Wt;
        const unsigned int* wq = wtu +                 ((w * 32 + c) << 6);
        const unsigned int* wk = wtu + (8 * 32 * 64) + ((w * 32 + c) << 6);
        const unsigned int* wv = wtu + (16 * 32 * 64) + ((w * 32 + c) << 6);
        for (int mc = 0; mc < 64; mc += 4) {
            uint4 q4 = *(const uint4*)(wq + mc);
            uint4 k4 = *(const uint4*)(wk + mc);
            uint4 v4 = *(const uint4*)(wv + mc);
            #pragma unroll
            for (int n = 0; n < 8; ++n) {
                uint4 z = *(const uint4*)&zh[(((nbase + n) * 8 + w) << 6) + mc];
                float a;
                a = qa[n]; a = dot2(z.x, q4.x, a); a = dot2(z.y, q4.y, a);
                a = dot2(z.z, q4.z, a); a = dot2(z.w, q4.w, a); qa[n] = a;
                a = ka[n]; a = dot2(z.x, k4.x, a); a = dot2(z.y, k4.y, a);
                a = dot2(z.z, k4.z, a); a = dot2(z.w, k4.w, a); ka[n] = a;
                a = va[n]; a = dot2(z.x, v4.x, a); a = dot2(z.y, v4.y, a);
                a = dot2(z.z, v4.z, a); a = dot2(z.w, v4.w, a); va[n] = a;
            }
        }
    }
    __syncthreads();   // zh reads done -> overlay q/k/v fp16 onto zh
    unsigned short* qh = (unsigned short*)zh;       // [n][r][32] fp16, 8 KB
    unsigned short* kh = qh + 4096;                 // 8 KB
    unsigned short* vh = qh + 8192;                 // 8 KB
    float* psi_l = (float*)sortbuf;                 // 4 KB (sort done)
    #pragma unroll
    for (int n = 0; n < 8; ++n) {
        int base = ((nbase + n) * 8 + w) * 32 + c;
        qh[base] = f2h(qa[n]);
        kh[base] = f2h(ka[n]);
        vh[base] = f2h(va[n]);
    }
    __syncthreads();

    // ---- psi[n][rr][ss] = <q[n,rr], k[n,ss]> (fp16 dot2) ----
    for (int idx = tid; idx < NB_ * 64; idx += 512) {
        int n = idx >> 6, rr = (idx >> 3) & 7, ss = idx & 7;
        const unsigned int* q4 = (const unsigned int*)(qh + (n * 8 + rr) * 32);
        const unsigned int* k4 = (const unsigned int*)(kh + (n * 8 + ss) * 32);
        float p = 0.f;
        #pragma unroll
        for (int c2 = 0; c2 < 16; c2 += 4) {
            uint4 a = *(const uint4*)(q4 + c2);
            uint4 b = *(const uint4*)(k4 + c2);
            p = dot2(a.x, b.x, p); p = dot2(a.y, b.y, p);
            p = dot2(a.z, b.z, p); p = dot2(a.w, b.w, p);
        }
        psi_l[idx] = p;
    }
    __syncthreads();
    if (tid < NB_ * 8) {
        float* row = &psi_l[tid * 8];
        float m = -INFINITY;
        #pragma unroll
        for (int s = 0; s < 8; ++s) m = fmaxf(m, row[s]);
        float sum = 0.f;
        #pragma unroll
        for (int s = 0; s < 8; ++s) { float e = __expf(row[s] - m); row[s] = e; sum += e; }
        float inv = 1.f / sum;
        #pragma unroll
        for (int s = 0; s < 8; ++s) row[s] *= inv;
    }
    __syncthreads();

    // ---- delta[n][r][c] = sum_s psi * v (wave w = relation) ----
    float dl[8];
    #pragma unroll
    for (int n = 0; n < 8; ++n) dl[n] = 0.f;
    #pragma unroll
    for (int s = 0; s < 8; ++s) {
        #pragma unroll
        for (int n = 0; n < 8; ++n) {
            float vv = h2f(vh[((nbase + n) * 8 + s) * 32 + c]);
            dl[n] += psi_l[(nbase + n) * 64 + w * 8 + s] * vv;
        }
    }
    __syncthreads();   // q/k reads done -> overlay delta fp32 (16 KB, vh safe)
    float* dbuf = (float*)zh;          // [n][r][32] fp32
    float* mskl = (float*)bcur;        // bcur dead after sort
    #pragma unroll
    for (int n = 0; n < 8; ++n)
        dbuf[((nbase + n) * 8 + w) * 32 + c] = dl[n];
    __syncthreads();

    // ---- mask[n][r] = (sum_c delta != 0) ----
    if (tid < NB_ * 8) {
        int n = tid >> 3, rr = tid & 7;
        float s = 0.f;
        #pragma unroll
        for (int cc = 0; cc < 32; ++cc) s += dbuf[(n * 8 + rr) * 32 + cc];
        mskl[tid] = (s != 0.f) ? 1.f : 0.f;
    }
    __syncthreads();

    // ---- out[n] = sum_r (delta + self_term*mask) * W_rel[r] ----
    {
        int n = tid >> 5, cc = tid & 31;   // 512 = 16 nodes x 32 cols
        if (n0 + n < N) {
            float st = out[(size_t)(n0 + n) * 32 + cc];
            float o = 0.f;
            #pragma unroll
            for (int rr = 0; rr < 8; ++rr)
                o += (dbuf[(n * 8 + rr) * 32 + cc] + st * mskl[n * 8 + rr]) * W_rel[rr];
            out[(size_t)(n0 + n) * 32 + cc] = o;
        }
    }
}

// -------------------------------------------------------------------------
extern "C" void kernel_launch(void* const* d_in, const int* in_sizes, int n_in,
                              void* d_out, int out_size, void* d_ws, size_t ws_size,
                              hipStream_t stream)
{
    const float* x      = (const float*)d_in[0];
    const int*   ei     = (const int*)  d_in[1];   // [2,E]
    const int*   et     = (const int*)  d_in[2];   // [E]
    const float* Wj     = (const float*)d_in[3];
    const float* Wi     = (const float*)d_in[4];
    const float* natt   = (const float*)d_in[5];
    const float* W_q    = (const float*)d_in[6];
    const float* W_k    = (const float*)d_in[7];
    const float* W_v    = (const float*)d_in[8];
    const float* W_self = (const float*)d_in[9];
    const float* W_sn   = (const float*)d_in[10];
    const float* W_rel  = (const float*)d_in[11];
    float* out = (float*)d_out;

    const int N = in_sizes[0] / INF_;
    const int E = in_sizes[2];
    const int G = (N + NB_ - 1) / NB_;   // 16-node groups

    // workspace layout (~42 MB)
    float* ws        = (float*)d_ws;
    float* AI        = ws;                               // N*32
    float* AJ        = AI + (size_t)N * 32;              // N*32
    unsigned short* hjb  = (unsigned short*)(AJ + (size_t)N * 32); // N*128 fp16
    unsigned short* sn16 = hjb + (size_t)N * 128;        // N*128 fp16
    unsigned short* Wt   = sn16 + (size_t)N * 128;       // 98304 fp16
    unsigned* Wp     = (unsigned*)(Wt + 98304);          // 352*64 uint
    int*   counts    = (int*)(Wp + 352 * 64);            // G+1
    int*   offsets   = counts + (G + 1);                 // G+1
    int*   cursor    = offsets + (G + 1);                // G
    int*   sorted    = cursor + G;                       // E

    // ---- prep (Wt + Wp incl. inline M + zero counts) ----
    const int prep_total = 98304 + 352 * 64 + (G + 1);
    prep_all<<<(prep_total + 255) / 256, 256, 0, stream>>>(
        W_q, W_k, W_v, Wj, Wi, W_sn, W_self, natt, Wt, Wp, counts, G);

    // ---- CSR build ----
    count_edges<<<(E + 255) / 256, 256, 0, stream>>>(ei, counts, E);
    scan_offsets<<<1, 1024, 0, stream>>>(counts, offsets, cursor, G);
    scatter_edges<<<(E + 255) / 256, 256, 0, stream>>>(ei, et, cursor, sorted, E);

    // ---- node feature GEMMs ----
    fused_gemm<<<(N + 31) / 32, 256, 0, stream>>>(
        x, Wp, hjb, sn16, out, AI, AJ, N);

    // ---- fused edge aggregation + tail ----
    edge_tail<<<G, 512, 0, stream>>>(
        hjb, sn16, AJ, AI, offsets, sorted, Wt, W_rel, out, N);
}